// Round 16
// baseline (3090.990 us; speedup 1.0000x reference)
//
#include <hip/hip_runtime.h>
#include <hip/hip_bf16.h>
#include <math.h>

#define D_MODEL 192
#define D_INNER 384
#define D_STATE 16
#define DT_RANK 12
#define DEPTH   24
#define SEQL    257
#define BATCH   32
#define NTOK    (BATCH*SEQL)   // 8224 = 32*257
#define NC      16             // sequence chunks for the scan
#define CL      17             // chunk length (16*17 = 272 >= 257)
#define CCH     32             // conv chunk

typedef unsigned short ushort_t;
using bf16x8 = __attribute__((ext_vector_type(8))) short;
using f32x4  = __attribute__((ext_vector_type(4))) float;

__device__ __forceinline__ ushort_t f2b(float f) {
    __hip_bfloat16 h = __float2bfloat16(f);
    return reinterpret_cast<ushort_t&>(h);
}
__device__ __forceinline__ float b2f(ushort_t u) {
    __hip_bfloat16 h;
    reinterpret_cast<ushort_t&>(h) = u;
    return __bfloat162float(h);
}
__device__ __forceinline__ float softplus_f(float v) {
    return (v > 20.f) ? v : log1pf(expf(v));
}
__device__ __forceinline__ float softplus_fast(float v) {
    float e = __expf(v);
    float lg = __logf(1.f + e);
    return (v > 20.f) ? v : lg;
}

// r^(n+1) for n=0..15 via log-depth products; out[n] = r^(n+1)
__device__ __forceinline__ void pow_ladder(float r1, float* dA) {
    float r2 = r1 * r1;
    float r3 = r2 * r1;
    float r4 = r2 * r2;
    float r8 = r4 * r4;
    float r12 = r8 * r4;
    dA[0] = r1;       dA[1] = r2;       dA[2] = r3;       dA[3] = r4;
    dA[4] = r4 * r1;  dA[5] = r4 * r2;  dA[6] = r4 * r3;  dA[7] = r8;
    dA[8] = r8 * r1;  dA[9] = r8 * r2;  dA[10] = r8 * r3; dA[11] = r12;
    dA[12] = r12 * r1; dA[13] = r12 * r2; dA[14] = r12 * r3; dA[15] = r8 * r8;
}

// ---------------- fp32 -> bf16 conversion ----------------
__global__ __launch_bounds__(256) void convert_k(const float* __restrict__ in, ushort_t* __restrict__ out, int n) {
    int i = (blockIdx.x * 256 + threadIdx.x) * 4;
    if (i + 3 < n) {
        float4 v = *(const float4*)(in + i);
        ushort4 o;
        o.x = f2b(v.x); o.y = f2b(v.y); o.z = f2b(v.z); o.w = f2b(v.w);
        *(ushort4*)(out + i) = o;
    } else {
        for (int j = i; j < n; j++) out[j] = f2b(in[j]);
    }
}

// ---------------- check A_log structure: A[n] == -(n+1) (S4D init) ----------------
__global__ __launch_bounds__(256) void checkA_k(const float* __restrict__ Al, const float* __restrict__ Alb,
                                                int* __restrict__ flag) {
    int i = blockIdx.x * 256 + threadIdx.x;
    const int total = DEPTH * 384 * 16;
    if (i >= total) return;
    int n = i & 15;
    float tgt = (float)(n + 1);
    float a = __expf(Al[i]);
    float b = __expf(Alb[i]);
    if (fabsf(a - tgt) > 1e-4f * tgt || fabsf(b - tgt) > 1e-4f * tgt) atomicAnd(flag, 0);
}

// ---------------- patch rearrange: x (B,3,256,256) -> Apatch bf16 (B*256, 768) ----------------
__global__ __launch_bounds__(256) void rearrange_k(const float* __restrict__ x, ushort_t* __restrict__ Ap) {
    size_t i = (size_t)blockIdx.x * 256 + threadIdx.x;
    const size_t total = (size_t)8192 * 768 / 4;
    if (i >= total) return;
    size_t o = i * 4;
    int bt  = (int)(o / 768);
    int rem = (int)(o % 768);
    int c  = rem >> 8;
    int r2 = rem & 255;
    int pi = r2 >> 4;
    int pj = r2 & 15;
    int b = bt >> 8;
    int t = bt & 255;
    int ph = t >> 4, pw = t & 15;
    size_t src = (((size_t)(b * 3 + c) * 256) + (size_t)(ph * 16 + pi)) * 256 + (pw * 16 + pj);
    float4 v = *(const float4*)(x + src);
    ushort4 ov;
    ov.x = f2b(v.x); ov.y = f2b(v.y); ov.z = f2b(v.z); ov.w = f2b(v.w);
    *(ushort4*)(Ap + o) = ov;
}

// ---------------- assemble: insert cls token, add patch bias + pos embed ----------------
__global__ __launch_bounds__(192) void assemble_k(const float* __restrict__ P, const float* __restrict__ pb,
                                                  const float* __restrict__ cls, const float* __restrict__ pos,
                                                  float* __restrict__ hb) {
    int o = threadIdx.x;
    int l = blockIdx.x;
    int b = blockIdx.y;
    float v;
    if (l == 128) {
        v = cls[o];
    } else {
        int t = (l < 128) ? l : l - 1;
        v = P[((size_t)b * 256 + t) * 192 + o] + pb[o];
    }
    hb[((size_t)b * SEQL + l) * 192 + o] = v + pos[l * 192 + o];
}

// ---------------- fused add + RMSNorm (used once, layer 0) ----------------
__global__ __launch_bounds__(192) void addnorm_k(float* res, const float* __restrict__ h,
                                                 const float* __restrict__ w, ushort_t* __restrict__ outp) {
    int row = blockIdx.x;
    int t = threadIdx.x;
    size_t idx = (size_t)row * 192 + t;
    float r = res[idx] + h[idx];
    res[idx] = r;
    float ss = r * r;
    #pragma unroll
    for (int o = 32; o > 0; o >>= 1) ss += __shfl_down(ss, o);
    __shared__ float ps[3];
    int wid = t >> 6;
    if ((t & 63) == 0) ps[wid] = ss;
    __syncthreads();
    float tot = ps[0] + ps[1] + ps[2];
    float inv = rsqrtf(tot / 192.f + 1e-5f);
    outp[idx] = f2b(r * inv * w[t]);
}

// ---------------- bf16 MFMA GEMM, BM=128/BN=64: C[M,N] = A[M,K] * W[N,K]^T ----------------
template<int OUTBF>
__global__ __launch_bounds__(256) void gemm_bf16(const ushort_t* __restrict__ A,
                                                 const ushort_t* __restrict__ W,
                                                 void* __restrict__ C,
                                                 int M, int N, int K, int ldc) {
    __shared__ ushort_t As[128 * 40];
    __shared__ ushort_t Bs[64 * 40];
    int tid = threadIdx.x;
    int m0 = blockIdx.y * 128, n0 = blockIdx.x * 64;
    int row = tid >> 2;
    int k8  = (tid & 3) * 8;
    int lane = tid & 63;
    int w = tid >> 6;
    int wr = w >> 1, wc = w & 1;
    int lr = lane & 15;
    int lk = (lane >> 4) * 8;
    f32x4 acc[4][2];
    #pragma unroll
    for (int i = 0; i < 4; i++)
        #pragma unroll
        for (int j = 0; j < 2; j++) acc[i][j] = (f32x4){0.f, 0.f, 0.f, 0.f};

    for (int k0 = 0; k0 < K; k0 += 32) {
        #pragma unroll
        for (int hhalf = 0; hhalf < 2; hhalf++) {
            int r = row + hhalf * 64;
            int m = m0 + r;
            bf16x8 v = {0,0,0,0,0,0,0,0};
            if (m < M) v = *(const bf16x8*)(A + (size_t)m * K + k0 + k8);
            *(bf16x8*)(&As[r * 40 + k8]) = v;
        }
        {
            int n = n0 + row;
            bf16x8 v = {0,0,0,0,0,0,0,0};
            if (n < N) v = *(const bf16x8*)(W + (size_t)n * K + k0 + k8);
            *(bf16x8*)(&Bs[row * 40 + k8]) = v;
        }
        __syncthreads();
        bf16x8 af[4], bfr[2];
        #pragma unroll
        for (int mi = 0; mi < 4; mi++)
            af[mi] = *(const bf16x8*)(&As[(wr * 64 + mi * 16 + lr) * 40 + lk]);
        #pragma unroll
        for (int ni = 0; ni < 2; ni++)
            bfr[ni] = *(const bf16x8*)(&Bs[(wc * 32 + ni * 16 + lr) * 40 + lk]);
        #pragma unroll
        for (int mi = 0; mi < 4; mi++)
            #pragma unroll
            for (int ni = 0; ni < 2; ni++)
                acc[mi][ni] = __builtin_amdgcn_mfma_f32_16x16x32_bf16(af[mi], bfr[ni], acc[mi][ni], 0, 0, 0);
        __syncthreads();
    }
    int rbase = (lane >> 4) * 4;
    #pragma unroll
    for (int mi = 0; mi < 4; mi++) {
        #pragma unroll
        for (int ni = 0; ni < 2; ni++) {
            #pragma unroll
            for (int r = 0; r < 4; r++) {
                int m = m0 + wr * 64 + mi * 16 + rbase + r;
                int n = n0 + wc * 32 + ni * 16 + lr;
                if (m < M && n < N) {
                    if (OUTBF) ((ushort_t*)C)[(size_t)m * ldc + n] = f2b(acc[mi][ni][r]);
                    else       ((float*)C)[(size_t)m * ldc + n] = acc[mi][ni][r];
                }
            }
        }
    }
}

// ---------------- bf16 MFMA GEMM, BM=128/BN=64, dual-dir (xproj) ----------------
__global__ __launch_bounds__(256) void gemm_xproj(const ushort_t* __restrict__ A0, const ushort_t* __restrict__ A1,
                                                  const ushort_t* __restrict__ W0, const ushort_t* __restrict__ W1,
                                                  float* __restrict__ C0, float* __restrict__ C1,
                                                  int M, int N, int K, int ldc) {
    __shared__ ushort_t As[128 * 40];
    __shared__ ushort_t Bs[64 * 40];
    int dir = blockIdx.z;
    const ushort_t* A = dir ? A1 : A0;
    const ushort_t* W = dir ? W1 : W0;
    float* C = dir ? C1 : C0;
    int tid = threadIdx.x;
    int m0 = blockIdx.y * 128, n0 = blockIdx.x * 64;
    int row = tid >> 2;
    int k8  = (tid & 3) * 8;
    int lane = tid & 63;
    int w = tid >> 6;
    int wr = w >> 1, wc = w & 1;
    int lr = lane & 15;
    int lk = (lane >> 4) * 8;
    f32x4 acc[4][2];
    #pragma unroll
    for (int i = 0; i < 4; i++)
        #pragma unroll
        for (int j = 0; j < 2; j++) acc[i][j] = (f32x4){0.f, 0.f, 0.f, 0.f};

    for (int k0 = 0; k0 < K; k0 += 32) {
        #pragma unroll
        for (int hhalf = 0; hhalf < 2; hhalf++) {
            int r = row + hhalf * 64;
            int m = m0 + r;
            bf16x8 v = {0,0,0,0,0,0,0,0};
            if (m < M) v = *(const bf16x8*)(A + (size_t)m * K + k0 + k8);
            *(bf16x8*)(&As[r * 40 + k8]) = v;
        }
        {
            int n = n0 + row;
            bf16x8 v = {0,0,0,0,0,0,0,0};
            if (n < N) v = *(const bf16x8*)(W + (size_t)n * K + k0 + k8);
            *(bf16x8*)(&Bs[row * 40 + k8]) = v;
        }
        __syncthreads();
        bf16x8 af[4], bfr[2];
        #pragma unroll
        for (int mi = 0; mi < 4; mi++)
            af[mi] = *(const bf16x8*)(&As[(wr * 64 + mi * 16 + lr) * 40 + lk]);
        #pragma unroll
        for (int ni = 0; ni < 2; ni++)
            bfr[ni] = *(const bf16x8*)(&Bs[(wc * 32 + ni * 16 + lr) * 40 + lk]);
        #pragma unroll
        for (int mi = 0; mi < 4; mi++)
            #pragma unroll
            for (int ni = 0; ni < 2; ni++)
                acc[mi][ni] = __builtin_amdgcn_mfma_f32_16x16x32_bf16(af[mi], bfr[ni], acc[mi][ni], 0, 0, 0);
        __syncthreads();
    }
    int rbase = (lane >> 4) * 4;
    #pragma unroll
    for (int mi = 0; mi < 4; mi++) {
        #pragma unroll
        for (int ni = 0; ni < 2; ni++) {
            #pragma unroll
            for (int r = 0; r < 4; r++) {
                int m = m0 + wr * 64 + mi * 16 + rbase + r;
                int n = n0 + wc * 32 + ni * 16 + lr;
                if (m < M && n < N) C[(size_t)m * ldc + n] = acc[mi][ni][r];
            }
        }
    }
}

// ---------------- out_proj GEMM BM=32/BN=192 + fused dir-combine + residual + RMSNorm ----------------
template<int FINAL>
__global__ __launch_bounds__(256) void gemm_outnorm(const ushort_t* __restrict__ yf, const ushort_t* __restrict__ yr,
                                                    const ushort_t* __restrict__ W, float* __restrict__ res,
                                                    const float* __restrict__ nw, void* __restrict__ outp) {
    __shared__ ushort_t As[32 * 40];
    __shared__ ushort_t Bs[192 * 40];
    __shared__ float psums[4 * 32];
    const int K = 384;
    int tid = threadIdx.x;
    int m0 = blockIdx.y * 32;
    int lane = tid & 63;
    int w = tid >> 6;
    int lr = lane & 15;
    int hi2 = lane >> 4;
    int lk = hi2 * 8;
    f32x4 acc[2][3];
    #pragma unroll
    for (int i = 0; i < 2; i++)
        #pragma unroll
        for (int j = 0; j < 3; j++) acc[i][j] = (f32x4){0.f, 0.f, 0.f, 0.f};

    int arow = tid >> 2;
    int k8 = (tid & 3) * 8;
    size_t rowfA = 0, rowrA = 0;
    if (tid < 128) {
        int m_ld = m0 + arow;
        int bb = m_ld / SEQL;
        int ll = m_ld - bb * SEQL;
        rowfA = (size_t)m_ld * 384;
        rowrA = ((size_t)bb * SEQL + (SEQL - 1 - ll)) * 384;
    }

    for (int k0 = 0; k0 < K; k0 += 32) {
        if (tid < 128) {
            bf16x8 vf = *(const bf16x8*)(yf + rowfA + k0 + k8);
            bf16x8 vr = *(const bf16x8*)(yr + rowrA + k0 + k8);
            bf16x8 v;
            #pragma unroll
            for (int j = 0; j < 8; j++) {
                float a = b2f((ushort_t)vf[j]);
                float b2 = b2f((ushort_t)vr[j]);
                v[j] = (short)f2b(0.5f * (a + b2));
            }
            *(bf16x8*)(&As[arow * 40 + k8]) = v;
        }
        #pragma unroll
        for (int s = 0; s < 3; s++) {
            int n = arow + s * 64;
            *(bf16x8*)(&Bs[n * 40 + k8]) = *(const bf16x8*)(W + (size_t)n * K + k0 + k8);
        }
        __syncthreads();
        bf16x8 af[2], bfr[3];
        #pragma unroll
        for (int mi = 0; mi < 2; mi++)
            af[mi] = *(const bf16x8*)(&As[(mi * 16 + lr) * 40 + lk]);
        #pragma unroll
        for (int ni = 0; ni < 3; ni++)
            bfr[ni] = *(const bf16x8*)(&Bs[(w * 48 + ni * 16 + lr) * 40 + lk]);
        #pragma unroll
        for (int mi = 0; mi < 2; mi++)
            #pragma unroll
            for (int ni = 0; ni < 3; ni++)
                acc[mi][ni] = __builtin_amdgcn_mfma_f32_16x16x32_bf16(af[mi], bfr[ni], acc[mi][ni], 0, 0, 0);
        __syncthreads();
    }

    #pragma unroll
    for (int mi = 0; mi < 2; mi++) {
        #pragma unroll
        for (int r = 0; r < 4; r++) {
            int m = m0 + mi * 16 + hi2 * 4 + r;
            #pragma unroll
            for (int ni = 0; ni < 3; ni++) {
                int col = w * 48 + ni * 16 + lr;
                acc[mi][ni][r] += res[(size_t)m * 192 + col];
            }
        }
    }
    float pp[2][4];
    #pragma unroll
    for (int mi = 0; mi < 2; mi++)
        #pragma unroll
        for (int r = 0; r < 4; r++) {
            float s = acc[mi][0][r] * acc[mi][0][r];
            s = fmaf(acc[mi][1][r], acc[mi][1][r], s);
            s = fmaf(acc[mi][2][r], acc[mi][2][r], s);
            pp[mi][r] = s;
        }
    #pragma unroll
    for (int mask = 1; mask < 16; mask <<= 1)
        #pragma unroll
        for (int mi = 0; mi < 2; mi++)
            #pragma unroll
            for (int r = 0; r < 4; r++)
                pp[mi][r] += __shfl_xor(pp[mi][r], mask);
    if (lr == 0) {
        #pragma unroll
        for (int mi = 0; mi < 2; mi++)
            #pragma unroll
            for (int r = 0; r < 4; r++)
                psums[w * 32 + mi * 16 + hi2 * 4 + r] = pp[mi][r];
    }
    __syncthreads();
    float inv[2][4];
    #pragma unroll
    for (int mi = 0; mi < 2; mi++)
        #pragma unroll
        for (int r = 0; r < 4; r++) {
            int idx = mi * 16 + hi2 * 4 + r;
            float tot = psums[idx] + psums[32 + idx] + psums[64 + idx] + psums[96 + idx];
            inv[mi][r] = rsqrtf(tot / 192.f + 1e-5f);
        }
    #pragma unroll
    for (int mi = 0; mi < 2; mi++) {
        #pragma unroll
        for (int ni = 0; ni < 3; ni++) {
            int col = w * 48 + ni * 16 + lr;
            float nwc = nw[col];
            #pragma unroll
            for (int r = 0; r < 4; r++) {
                int m = m0 + mi * 16 + hi2 * 4 + r;
                float v = acc[mi][ni][r];
                if (!FINAL) res[(size_t)m * 192 + col] = v;
                float o = v * inv[mi][r] * nwc;
                if (FINAL) ((float*)outp)[(size_t)m * 192 + col] = o;
                else       ((ushort_t*)outp)[(size_t)m * 192 + col] = f2b(o);
            }
        }
    }
}

// ---------------- causal depthwise conv (k=4) + SiLU, 2 channels/thread, both dirs ----------------
__global__ __launch_bounds__(192) void conv_silu_k(const ushort_t* __restrict__ xz,
                                                   const float* __restrict__ cw, const float* __restrict__ cb,
                                                   const float* __restrict__ cwb, const float* __restrict__ cbb,
                                                   ushort_t* __restrict__ xcf, ushort_t* __restrict__ xcr) {
    int t = threadIdx.x;
    int d0 = t, d1 = t + 192;
    int lc = blockIdx.x;
    int b = blockIdx.y;
    int dir = blockIdx.z;
    int lstart = lc * CCH;
    int lend = (lstart + CCH < SEQL) ? (lstart + CCH) : SEQL;
    const float* w = dir ? cwb : cw;
    const float* bias = dir ? cbb : cb;
    float4 wv0 = *(const float4*)(w + d0 * 4);
    float4 wv1 = *(const float4*)(w + d1 * 4);
    float bs0 = bias[d0];
    float bs1 = bias[d1];
    ushort_t* out = dir ? xcr : xcf;
    size_t base = (size_t)b * SEQL;
    float a0w0 = 0.f, a0w1 = 0.f, a0w2 = 0.f;
    float a1w0 = 0.f, a1w1 = 0.f, a1w2 = 0.f;
    if (lstart - 3 >= 0) { size_t r = (base + (dir ? (SEQL-1-(lstart-3)) : (lstart-3))) * 768; a0w0 = b2f(xz[r + d0]); a1w0 = b2f(xz[r + d1]); }
    if (lstart - 2 >= 0) { size_t r = (base + (dir ? (SEQL-1-(lstart-2)) : (lstart-2))) * 768; a0w1 = b2f(xz[r + d0]); a1w1 = b2f(xz[r + d1]); }
    if (lstart - 1 >= 0) { size_t r = (base + (dir ? (SEQL-1-(lstart-1)) : (lstart-1))) * 768; a0w2 = b2f(xz[r + d0]); a1w2 = b2f(xz[r + d1]); }
    size_t rc = (base + (dir ? (SEQL-1-lstart) : lstart)) * 768;
    float x0c = b2f(xz[rc + d0]);
    float x1c = b2f(xz[rc + d1]);
    for (int l = lstart; l < lend; l++) {
        int ln = l + 1;
        float x0n = 0.f, x1n = 0.f;
        if (ln < lend) {
            size_t rn = (base + (dir ? (SEQL-1-ln) : ln)) * 768;
            x0n = b2f(xz[rn + d0]);
            x1n = b2f(xz[rn + d1]);
        }
        float a0 = bs0, a1 = bs1;
        a0 = fmaf(wv0.x, a0w0, a0); a0 = fmaf(wv0.y, a0w1, a0); a0 = fmaf(wv0.z, a0w2, a0); a0 = fmaf(wv0.w, x0c, a0);
        a1 = fmaf(wv1.x, a1w0, a1); a1 = fmaf(wv1.y, a1w1, a1); a1 = fmaf(wv1.z, a1w2, a1); a1 = fmaf(wv1.w, x1c, a1);
        float s0 = a0 / (1.f + __expf(-a0));
        float s1 = a1 / (1.f + __expf(-a1));
        out[(base + l) * 384 + d0] = f2b(s0);
        out[(base + l) * 384 + d1] = f2b(s1);
        a0w0 = a0w1; a0w1 = a0w2; a0w2 = x0c; x0c = x0n;
        a1w0 = a1w1; a1w1 = a1w2; a1w2 = x1c; x1c = x1n;
    }
}

// ============ chunked selective scan: 2 channels/thread, rows direct-from-global ============
__global__ __launch_bounds__(192) void scan_p1(const ushort_t* __restrict__ xcf, const ushort_t* __restrict__ xcr,
                                               const float* __restrict__ dtbcf, const float* __restrict__ dtbcr,
                                               const float* __restrict__ dwf, const float* __restrict__ dwr,
                                               const float* __restrict__ dbf, const float* __restrict__ dbr,
                                               const float* __restrict__ Alf, const float* __restrict__ Alb,
                                               float* __restrict__ Sbuf, float* __restrict__ sumdt,
                                               const int* __restrict__ flagp) {
    int t = threadIdx.x;
    int d0 = t, d1 = t + 192;
    int c = blockIdx.x;
    int b = blockIdx.y, dir = blockIdx.z;
    int bd = b * 2 + dir;
    const ushort_t* xcp = dir ? xcr : xcf;
    const float* pbc = (dir ? dtbcr : dtbcf) + (size_t)b * SEQL * 44;
    int lstart = c * CL;
    int clen = (lstart + CL < SEQL) ? CL : (SEQL - lstart);
    size_t rowbase = (size_t)b * SEQL + lstart;

    float dw0[12], dw1[12];
    {
        const float* dwp = (dir ? dwr : dwf);
        #pragma unroll
        for (int r = 0; r < 12; r++) dw0[r] = dwp[d0 * 12 + r];
        #pragma unroll
        for (int r = 0; r < 12; r++) dw1[r] = dwp[d1 * 12 + r];
    }
    float db0 = (dir ? dbr : dbf)[d0];
    float db1 = (dir ? dbr : dbf)[d1];
    bool fast = (*flagp != 0);
    float S0[16], S1[16];
    #pragma unroll
    for (int n = 0; n < 16; n++) { S0[n] = 0.f; S1[n] = 0.f; }
    float ss0 = 0.f, ss1 = 0.f;

    if (fast) {
        float x0 = b2f(xcp[rowbase * 384 + d0]);
        float x1 = b2f(xcp[rowbase * 384 + d1]);
        for (int l = 0; l < clen; l++) {
            int ln = (l + 1 < clen) ? (l + 1) : l;
            float x0n = b2f(xcp[(rowbase + ln) * 384 + d0]);
            float x1n = b2f(xcp[(rowbase + ln) * 384 + d1]);
            const float* rp = pbc + (size_t)(lstart + l) * 44;   // wave-uniform
            float4 t0 = *(const float4*)(rp);
            float4 t1 = *(const float4*)(rp + 4);
            float4 t2 = *(const float4*)(rp + 8);
            float4 B0 = *(const float4*)(rp + 12);
            float4 B1 = *(const float4*)(rp + 16);
            float4 B2 = *(const float4*)(rp + 20);
            float4 B3 = *(const float4*)(rp + 24);
            float tv[12] = {t0.x,t0.y,t0.z,t0.w, t1.x,t1.y,t1.z,t1.w, t2.x,t2.y,t2.z,t2.w};
            float a0 = db0, a1 = db1;
            #pragma unroll
            for (int r = 0; r < 12; r++) {
                a0 = fmaf(tv[r], dw0[r], a0);
                a1 = fmaf(tv[r], dw1[r], a1);
            }
            float dt0 = softplus_fast(a0);
            float dt1 = softplus_fast(a1);
            ss0 += dt0; ss1 += dt1;
            float dtx0 = dt0 * x0, dtx1 = dt1 * x1;
            float dA0[16], dA1[16];
            pow_ladder(__expf(-dt0), dA0);
            pow_ladder(__expf(-dt1), dA1);
            float Bv[16] = {B0.x,B0.y,B0.z,B0.w, B1.x,B1.y,B1.z,B1.w,
                            B2.x,B2.y,B2.z,B2.w, B3.x,B3.y,B3.z,B3.w};
            #pragma unroll
            for (int n = 0; n < 16; n++) {
                S0[n] = fmaf(S0[n], dA0[n], dtx0 * Bv[n]);
                S1[n] = fmaf(S1[n], dA1[n], dtx1 * Bv[n]);
            }
            x0 = x0n; x1 = x1n;
        }
    } else {
        const float* alog = (dir ? Alb : Alf);
        float A0[16], A1[16];
        #pragma unroll
        for (int n = 0; n < 16; n++) A0[n] = -__expf(alog[d0 * 16 + n]);
        #pragma unroll
        for (int n = 0; n < 16; n++) A1[n] = -__expf(alog[d1 * 16 + n]);
        for (int l = 0; l < clen; l++) {
            const float* rp = pbc + (size_t)(lstart + l) * 44;
            float a0 = db0, a1 = db1;
            #pragma unroll
            for (int r = 0; r < 12; r++) {
                a0 = fmaf(rp[r], dw0[r], a0);
                a1 = fmaf(rp[r], dw1[r], a1);
            }
            float dt0 = softplus_f(a0);
            float dt1 = softplus_f(a1);
            ss0 += dt0; ss1 += dt1;
            float x0 = b2f(xcp[(rowbase + l) * 384 + d0]);
            float x1 = b2f(xcp[(rowbase + l) * 384 + d1]);
            float dtx0 = dt0 * x0, dtx1 = dt1 * x1;
            #pragma unroll
            for (int n = 0; n < 16; n++) {
                S0[n] = fmaf(S0[n], __expf(dt0 * A0[n]), dtx0 * rp[12 + n]);
                S1[n] = fmaf(S1[n], __expf(dt1 * A1[n]), dtx1 * rp[12 + n]);
            }
        }
    }
    float* spb = Sbuf + ((size_t)bd * NC + c) * 6144;
    #pragma unroll
    for (int j = 0; j < 4; j++) {
        *(float4*)(spb + d0 * 16 + j * 4) = make_float4(S0[j*4], S0[j*4+1], S0[j*4+2], S0[j*4+3]);
        *(float4*)(spb + d1 * 16 + j * 4) = make_float4(S1[j*4], S1[j*4+1], S1[j*4+2], S1[j*4+3]);
    }
    sumdt[((size_t)bd * NC + c) * 384 + d0] = ss0;
    sumdt[((size_t)bd * NC + c) * 384 + d1] = ss1;
}

// pass 2: O(NC) prefix; converts Sbuf in place into h_in per chunk. 1 thread per (bd,d,n).
__global__ __launch_bounds__(256) void scan_mid(float* __restrict__ Sbuf, const float* __restrict__ sumdt,
                                                const float* __restrict__ Alf, const float* __restrict__ Alb,
                                                const int* __restrict__ flagp) {
    int gid = blockIdx.x * 256 + threadIdx.x;
    int n = gid & 15;
    int rest = gid >> 4;
    int d = rest % 384;
    int bd = rest / 384;
    int dir = bd & 1;
    bool fast = (*flagp != 0);
    float A = fast ? -(float)(n + 1) : -__expf((dir ? Alb : Alf)[d * 16 + n]);
    float h = 0.f;
    #pragma unroll
    for (int c = 0; c < NC; c++) {
        size_t si = ((size_t)bd * NC + c) * 6144 + d * 16 + n;
        float S = Sbuf[si];
        float sd = sumdt[((size_t)bd * NC + c) * 384 + d];
        Sbuf[si] = h;
        h = fmaf(h, __expf(A * sd), S);
    }
}

// pass 3: read own h_in, re-scan chunk, emit y*silu(z) bf16. 2 channels/thread.
__global__ __launch_bounds__(192) void scan_p3(const ushort_t* __restrict__ xcf, const ushort_t* __restrict__ xcr,
                                               const float* __restrict__ dtbcf, const float* __restrict__ dtbcr,
                                               const float* __restrict__ dwf, const float* __restrict__ dwr,
                                               const float* __restrict__ dbf, const float* __restrict__ dbr,
                                               const float* __restrict__ Alf, const float* __restrict__ Alb,
                                               const float* __restrict__ Df, const float* __restrict__ Db,
                                               const ushort_t* __restrict__ xz,
                                               const float* __restrict__ Sbuf,
                                               ushort_t* __restrict__ ybf, ushort_t* __restrict__ ybr,
                                               const int* __restrict__ flagp) {
    int t = threadIdx.x;
    int d0 = t, d1 = t + 192;
    int c = blockIdx.x;
    int b = blockIdx.y, dir = blockIdx.z;
    int bd = b * 2 + dir;
    const ushort_t* xcp = dir ? xcr : xcf;
    const float* pbc = (dir ? dtbcr : dtbcf) + (size_t)b * SEQL * 44;
    ushort_t* yb = dir ? ybr : ybf;
    int lstart = c * CL;
    int clen = (lstart + CL < SEQL) ? CL : (SEQL - lstart);
    size_t rowbase = (size_t)b * SEQL + lstart;
    size_t seqbase = (size_t)b * SEQL;

    float dw0[12], dw1[12];
    {
        const float* dwp = (dir ? dwr : dwf);
        #pragma unroll
        for (int r = 0; r < 12; r++) dw0[r] = dwp[d0 * 12 + r];
        #pragma unroll
        for (int r = 0; r < 12; r++) dw1[r] = dwp[d1 * 12 + r];
    }
    float db0 = (dir ? dbr : dbf)[d0];
    float db1 = (dir ? dbr : dbf)[d1];
    float Dp0 = (dir ? Db : Df)[d0];
    float Dp1 = (dir ? Db : Df)[d1];
    bool fast = (*flagp != 0);
    float h0[16], h1[16];
    {
        const float* spb = Sbuf + ((size_t)bd * NC + c) * 6144;
        #pragma unroll
        for (int j = 0; j < 4; j++) {
            float4 hv0 = *(const float4*)(spb + d0 * 16 + j * 4);
            float4 hv1 = *(const float4*)(spb + d1 * 16 + j * 4);
            h0[j*4] = hv0.x; h0[j*4+1] = hv0.y; h0[j*4+2] = hv0.z; h0[j*4+3] = hv0.w;
            h1[j*4] = hv1.x; h1[j*4+1] = hv1.y; h1[j*4+2] = hv1.z; h1[j*4+3] = hv1.w;
        }
    }

    if (fast) {
        float x0 = b2f(xcp[rowbase * 384 + d0]);
        float x1 = b2f(xcp[rowbase * 384 + d1]);
        size_t zr0 = (dir ? (seqbase + SEQL - 1 - lstart) : rowbase) * 768 + 384;
        float z0 = b2f(xz[zr0 + d0]);
        float z1 = b2f(xz[zr0 + d1]);
        for (int l = 0; l < clen; l++) {
            int ln = (l + 1 < clen) ? (l + 1) : l;
            float x0n = b2f(xcp[(rowbase + ln) * 384 + d0]);
            float x1n = b2f(xcp[(rowbase + ln) * 384 + d1]);
            size_t zrn = (dir ? (seqbase + SEQL - 1 - (lstart + ln)) : (rowbase + ln)) * 768 + 384;
            float z0n = b2f(xz[zrn + d0]);
            float z1n = b2f(xz[zrn + d1]);
            const float* rp = pbc + (size_t)(lstart + l) * 44;   // wave-uniform
            float4 t0 = *(const float4*)(rp);
            float4 t1 = *(const float4*)(rp + 4);
            float4 t2 = *(const float4*)(rp + 8);
            float4 B0 = *(const float4*)(rp + 12);
            float4 B1 = *(const float4*)(rp + 16);
            float4 B2 = *(const float4*)(rp + 20);
            float4 B3 = *(const float4*)(rp + 24);
            float4 C0 = *(const float4*)(rp + 28);
            float4 C1 = *(const float4*)(rp + 32);
            float4 C2 = *(const float4*)(rp + 36);
            float4 C3 = *(const float4*)(rp + 40);
            float tv[12] = {t0.x,t0.y,t0.z,t0.w, t1.x,t1.y,t1.z,t1.w, t2.x,t2.y,t2.z,t2.w};
            float a0 = db0, a1 = db1;
            #pragma unroll
            for (int r = 0; r < 12; r++) {
                a0 = fmaf(tv[r], dw0[r], a0);
                a1 = fmaf(tv[r], dw1[r], a1);
            }
            float dt0 = softplus_fast(a0);
            float dt1 = softplus_fast(a1);
            float dtx0 = dt0 * x0, dtx1 = dt1 * x1;
            float dA0[16], dA1[16];
            pow_ladder(__expf(-dt0), dA0);
            pow_ladder(__expf(-dt1), dA1);
            float Bv[16] = {B0.x,B0.y,B0.z,B0.w, B1.x,B1.y,B1.z,B1.w,
                            B2.x,B2.y,B2.z,B2.w, B3.x,B3.y,B3.z,B3.w};
            float Cv[16] = {C0.x,C0.y,C0.z,C0.w, C1.x,C1.y,C1.z,C1.w,
                            C2.x,C2.y,C2.z,C2.w, C3.x,C3.y,C3.z,C3.w};
            float y0 = 0.f, y1 = 0.f;
            #pragma unroll
            for (int n = 0; n < 16; n++) {
                h0[n] = fmaf(h0[n], dA0[n], dtx0 * Bv[n]);
                h1[n] = fmaf(h1[n], dA1[n], dtx1 * Bv[n]);
                y0 = fmaf(h0[n], Cv[n], y0);
                y1 = fmaf(h1[n], Cv[n], y1);
            }
            y0 = fmaf(Dp0, x0, y0);
            y1 = fmaf(Dp1, x1, y1);
            float sz0 = z0 / (1.f + __expf(-z0));
            float sz1 = z1 / (1.f + __expf(-z1));
            yb[(rowbase + l) * 384 + d0] = f2b(y0 * sz0);
            yb[(rowbase + l) * 384 + d1] = f2b(y1 * sz1);
            x0 = x0n; x1 = x1n; z0 = z0n; z1 = z1n;
        }
    } else {
        const float* alog = (dir ? Alb : Alf);
        float A0[16], A1[16];
        #pragma unroll
        for (int n = 0; n < 16; n++) A0[n] = -__expf(alog[d0 * 16 + n]);
        #pragma unroll
        for (int n = 0; n < 16; n++) A1[n] = -__expf(alog[d1 * 16 + n]);
        for (int l = 0; l < clen; l++) {
            const float* rp = pbc + (size_t)(lstart + l) * 44;
            float a0 = db0, a1 = db1;
            #pragma unroll
            for (int r = 0; r < 12; r++) {
                a0 = fmaf(rp[r], dw0[r], a0);
                a1 = fmaf(rp[r], dw1[r], a1);
            }
            float dt0 = softplus_f(a0);
            float dt1 = softplus_f(a1);
            float x0 = b2f(xcp[(rowbase + l) * 384 + d0]);
            float x1 = b2f(xcp[(rowbase + l) * 384 + d1]);
            size_t zr = (dir ? (seqbase + SEQL - 1 - (lstart + l)) : (rowbase + l)) * 768 + 384;
            float z0 = b2f(xz[zr + d0]);
            float z1 = b2f(xz[zr + d1]);
            float dtx0 = dt0 * x0, dtx1 = dt1 * x1;
            float y0 = 0.f, y1 = 0.f;
            #pragma unroll
            for (int n = 0; n < 16; n++) {
                h0[n] = fmaf(h0[n], __expf(dt0 * A0[n]), dtx0 * rp[12 + n]);
                h1[n] = fmaf(h1[n], __expf(dt1 * A1[n]), dtx1 * rp[12 + n]);
                y0 = fmaf(h0[n], rp[28 + n], y0);
                y1 = fmaf(h1[n], rp[28 + n], y1);
            }
            y0 = fmaf(Dp0, x0, y0);
            y1 = fmaf(Dp1, x1, y1);
            float sz0 = z0 / (1.f + __expf(-z0));
            float sz1 = z1 / (1.f + __expf(-z1));
            yb[(rowbase + l) * 384 + d0] = f2b(y0 * sz0);
            yb[(rowbase + l) * 384 + d1] = f2b(y1 * sz1);
        }
    }
}

extern "C" void kernel_launch(void* const* d_in, const int* in_sizes, int n_in,
                              void* d_out, int out_size, void* d_ws, size_t ws_size,
                              hipStream_t stream) {
    const float* x         = (const float*)d_in[0];
    const float* patch_w   = (const float*)d_in[1];
    const float* patch_b   = (const float*)d_in[2];
    const float* cls_token = (const float*)d_in[3];
    const float* pos_embed = (const float*)d_in[4];
    const float* norm_w    = (const float*)d_in[5];
    const float* in_proj_w = (const float*)d_in[6];
    const float* conv_w    = (const float*)d_in[7];
    const float* conv_b    = (const float*)d_in[8];
    const float* xproj_w   = (const float*)d_in[9];
    const float* dtproj_w  = (const float*)d_in[10];
    const float* dt_bias   = (const float*)d_in[11];
    const float* A_log     = (const float*)d_in[12];
    const float* Dskip     = (const float*)d_in[13];
    const float* conv_w_b  = (const float*)d_in[14];
    const float* conv_b_b  = (const float*)d_in[15];
    const float* xproj_w_b = (const float*)d_in[16];
    const float* dtproj_w_b= (const float*)d_in[17];
    const float* dt_bias_b = (const float*)d_in[18];
    const float* A_log_b   = (const float*)d_in[19];
    const float* Dskip_b   = (const float*)d_in[20];
    const float* out_proj_w= (const float*)d_in[21];
    const float* norm_f_w  = (const float*)d_in[22];

    float* ws = (float*)d_ws;
    size_t off = 0;
    float* res   = ws + off; off += (size_t)NTOK * 192;
    float* hbuf  = ws + off; off += (size_t)NTOK * 192;
    ushort_t* xzb = (ushort_t*)(ws + off); off += (size_t)NTOK * 384;   // NTOK*768 ushorts; also Apatch
    ushort_t* hnb = (ushort_t*)(ws + off); off += (size_t)NTOK * 96;
    ushort_t* xcfb = (ushort_t*)(ws + off); off += (size_t)NTOK * 192;
    ushort_t* xcrb = (ushort_t*)(ws + off); off += (size_t)NTOK * 192;
    float* dtbcf = ws + off; off += (size_t)NTOK * 44;
    float* dtbcr = ws + off; off += (size_t)NTOK * 44;
    ushort_t* ybf = (ushort_t*)(ws + off); off += (size_t)NTOK * 192;
    ushort_t* ybr = (ushort_t*)(ws + off); off += (size_t)NTOK * 192;
    float* Sbuf  = ws + off; off += (size_t)BATCH * 2 * NC * 6144;      // also Ppatch fp32
    float* sumdt = ws + off; off += (size_t)BATCH * 2 * NC * 384;
    int* flagp   = (int*)(ws + off); off += 4;
    ushort_t* wb = (ushort_t*)(ws + off);
    ushort_t* winb   = wb;
    ushort_t* woutb  = winb  + 3538944;
    ushort_t* xpfb   = woutb + 1769472;
    ushort_t* xprb   = xpfb  + 405504;
    ushort_t* patchwb= xprb  + 405504;

    ushort_t* Apatch = xzb;
    float* Ppatch = Sbuf;

    convert_k<<<(3538944/4 + 255)/256, 256, 0, stream>>>(in_proj_w, winb, 3538944);
    convert_k<<<(1769472/4 + 255)/256, 256, 0, stream>>>(out_proj_w, woutb, 1769472);
    convert_k<<<(405504/4 + 255)/256, 256, 0, stream>>>(xproj_w, xpfb, 405504);
    convert_k<<<(405504/4 + 255)/256, 256, 0, stream>>>(xproj_w_b, xprb, 405504);
    convert_k<<<(147456/4 + 255)/256, 256, 0, stream>>>(patch_w, patchwb, 147456);

    hipMemsetAsync(res, 0, (size_t)NTOK * 192 * sizeof(float), stream);
    hipMemsetAsync(flagp, 1, 4, stream);   // nonzero = fast path allowed
    checkA_k<<<(DEPTH*384*16 + 255)/256, 256, 0, stream>>>(A_log, A_log_b, flagp);

    rearrange_k<<<6144, 256, 0, stream>>>(x, Apatch);
    gemm_bf16<0><<<dim3(3, 64), 256, 0, stream>>>(Apatch, patchwb, Ppatch, 8192, 192, 768, 192);
    assemble_k<<<dim3(SEQL, BATCH), 192, 0, stream>>>(Ppatch, patch_b, cls_token, pos_embed, hbuf);
    addnorm_k<<<NTOK, 192, 0, stream>>>(res, hbuf, norm_w, hnb);   // layer-0 norm

    for (int i = 0; i < DEPTH; i++) {
        const float* cwf  = conv_w + (size_t)i * 384 * 4;
        const float* cbf  = conv_b + (size_t)i * 384;
        const float* cwr  = conv_w_b + (size_t)i * 384 * 4;
        const float* cbr  = conv_b_b + (size_t)i * 384;
        const float* dpf  = dtproj_w + (size_t)i * 384 * 12;
        const float* dpr  = dtproj_w_b + (size_t)i * 384 * 12;
        const float* dbf  = dt_bias + (size_t)i * 384;
        const float* dbr  = dt_bias_b + (size_t)i * 384;
        const float* alf  = A_log + (size_t)i * 384 * 16;
        const float* alr  = A_log_b + (size_t)i * 384 * 16;
        const float* dsf  = Dskip + (size_t)i * 384;
        const float* dsr  = Dskip_b + (size_t)i * 384;

        gemm_bf16<1><<<dim3(12, 65), 256, 0, stream>>>(hnb, winb + (size_t)i * 768 * 192, xzb,
                                                       NTOK, 768, 192, 768);
        conv_silu_k<<<dim3((SEQL + CCH - 1) / CCH, BATCH, 2), 192, 0, stream>>>(xzb, cwf, cbf, cwr, cbr, xcfb, xcrb);
        gemm_xproj<<<dim3(1, 65, 2), 256, 0, stream>>>(xcfb, xcrb,
                                                       xpfb + (size_t)i * 44 * 384, xprb + (size_t)i * 44 * 384,
                                                       dtbcf, dtbcr, NTOK, 44, 384, 44);
        scan_p1<<<dim3(NC, BATCH, 2), 192, 0, stream>>>(xcfb, xcrb, dtbcf, dtbcr,
                                                        dpf, dpr, dbf, dbr, alf, alr, Sbuf, sumdt, flagp);
        scan_mid<<<(BATCH * 2 * 384 * 16) / 256, 256, 0, stream>>>(Sbuf, sumdt, alf, alr, flagp);
        scan_p3<<<dim3(NC, BATCH, 2), 192, 0, stream>>>(xcfb, xcrb, dtbcf, dtbcr,
                                                        dpf, dpr, dbf, dbr, alf, alr, dsf, dsr,
                                                        xzb, Sbuf, ybf, ybr, flagp);
        if (i < DEPTH - 1) {
            gemm_outnorm<0><<<dim3(1, NTOK / 32), 256, 0, stream>>>(ybf, ybr, woutb + (size_t)i * 192 * 384,
                                                                    res, norm_w + (size_t)(i + 1) * 192, hnb);
        } else {
            gemm_outnorm<1><<<dim3(1, NTOK / 32), 256, 0, stream>>>(ybf, ybr, woutb + (size_t)i * 192 * 384,
                                                                    res, norm_f_w, (float*)d_out);
        }
    }
}

// Round 17
// 2989.292 us; speedup vs baseline: 1.0340x; 1.0340x over previous
//
#include <hip/hip_runtime.h>
#include <hip/hip_bf16.h>
#include <math.h>

#define D_MODEL 192
#define D_INNER 384
#define D_STATE 16
#define DT_RANK 12
#define DEPTH   24
#define SEQL    257
#define BATCH   32
#define NTOK    (BATCH*SEQL)   // 8224 = 32*257
#define NC      16             // sequence chunks for the scan
#define CL      17             // chunk length (16*17 = 272 >= 257)
#define CCH     32             // conv chunk

typedef unsigned short ushort_t;
using bf16x8 = __attribute__((ext_vector_type(8))) short;
using f32x4  = __attribute__((ext_vector_type(4))) float;

__device__ __forceinline__ ushort_t f2b(float f) {
    __hip_bfloat16 h = __float2bfloat16(f);
    return reinterpret_cast<ushort_t&>(h);
}
__device__ __forceinline__ float b2f(ushort_t u) {
    __hip_bfloat16 h;
    reinterpret_cast<ushort_t&>(h) = u;
    return __bfloat162float(h);
}
__device__ __forceinline__ float softplus_f(float v) {
    return (v > 20.f) ? v : log1pf(expf(v));
}
__device__ __forceinline__ float softplus_fast(float v) {
    float e = __expf(v);
    float lg = __logf(1.f + e);
    return (v > 20.f) ? v : lg;
}

// r^(n+1) for n=0..15 via log-depth products; out[n] = r^(n+1)
__device__ __forceinline__ void pow_ladder(float r1, float* dA) {
    float r2 = r1 * r1;
    float r3 = r2 * r1;
    float r4 = r2 * r2;
    float r8 = r4 * r4;
    float r12 = r8 * r4;
    dA[0] = r1;       dA[1] = r2;       dA[2] = r3;       dA[3] = r4;
    dA[4] = r4 * r1;  dA[5] = r4 * r2;  dA[6] = r4 * r3;  dA[7] = r8;
    dA[8] = r8 * r1;  dA[9] = r8 * r2;  dA[10] = r8 * r3; dA[11] = r12;
    dA[12] = r12 * r1; dA[13] = r12 * r2; dA[14] = r12 * r3; dA[15] = r8 * r8;
}

// ---------------- fp32 -> bf16 conversion ----------------
__global__ __launch_bounds__(256) void convert_k(const float* __restrict__ in, ushort_t* __restrict__ out, int n) {
    int i = (blockIdx.x * 256 + threadIdx.x) * 4;
    if (i + 3 < n) {
        float4 v = *(const float4*)(in + i);
        ushort4 o;
        o.x = f2b(v.x); o.y = f2b(v.y); o.z = f2b(v.z); o.w = f2b(v.w);
        *(ushort4*)(out + i) = o;
    } else {
        for (int j = i; j < n; j++) out[j] = f2b(in[j]);
    }
}

// ---------------- check A_log structure: A[n] == -(n+1) (S4D init) ----------------
__global__ __launch_bounds__(256) void checkA_k(const float* __restrict__ Al, const float* __restrict__ Alb,
                                                int* __restrict__ flag) {
    int i = blockIdx.x * 256 + threadIdx.x;
    const int total = DEPTH * 384 * 16;
    if (i >= total) return;
    int n = i & 15;
    float tgt = (float)(n + 1);
    float a = __expf(Al[i]);
    float b = __expf(Alb[i]);
    if (fabsf(a - tgt) > 1e-4f * tgt || fabsf(b - tgt) > 1e-4f * tgt) atomicAnd(flag, 0);
}

// ---------------- patch rearrange: x (B,3,256,256) -> Apatch bf16 (B*256, 768) ----------------
__global__ __launch_bounds__(256) void rearrange_k(const float* __restrict__ x, ushort_t* __restrict__ Ap) {
    size_t i = (size_t)blockIdx.x * 256 + threadIdx.x;
    const size_t total = (size_t)8192 * 768 / 4;
    if (i >= total) return;
    size_t o = i * 4;
    int bt  = (int)(o / 768);
    int rem = (int)(o % 768);
    int c  = rem >> 8;
    int r2 = rem & 255;
    int pi = r2 >> 4;
    int pj = r2 & 15;
    int b = bt >> 8;
    int t = bt & 255;
    int ph = t >> 4, pw = t & 15;
    size_t src = (((size_t)(b * 3 + c) * 256) + (size_t)(ph * 16 + pi)) * 256 + (pw * 16 + pj);
    float4 v = *(const float4*)(x + src);
    ushort4 ov;
    ov.x = f2b(v.x); ov.y = f2b(v.y); ov.z = f2b(v.z); ov.w = f2b(v.w);
    *(ushort4*)(Ap + o) = ov;
}

// ---------------- assemble: insert cls token, add patch bias + pos embed ----------------
__global__ __launch_bounds__(192) void assemble_k(const float* __restrict__ P, const float* __restrict__ pb,
                                                  const float* __restrict__ cls, const float* __restrict__ pos,
                                                  float* __restrict__ hb) {
    int o = threadIdx.x;
    int l = blockIdx.x;
    int b = blockIdx.y;
    float v;
    if (l == 128) {
        v = cls[o];
    } else {
        int t = (l < 128) ? l : l - 1;
        v = P[((size_t)b * 256 + t) * 192 + o] + pb[o];
    }
    hb[((size_t)b * SEQL + l) * 192 + o] = v + pos[l * 192 + o];
}

// ---------------- fused add + RMSNorm (used once, layer 0) ----------------
__global__ __launch_bounds__(192) void addnorm_k(float* res, const float* __restrict__ h,
                                                 const float* __restrict__ w, ushort_t* __restrict__ outp) {
    int row = blockIdx.x;
    int t = threadIdx.x;
    size_t idx = (size_t)row * 192 + t;
    float r = res[idx] + h[idx];
    res[idx] = r;
    float ss = r * r;
    #pragma unroll
    for (int o = 32; o > 0; o >>= 1) ss += __shfl_down(ss, o);
    __shared__ float ps[3];
    int wid = t >> 6;
    if ((t & 63) == 0) ps[wid] = ss;
    __syncthreads();
    float tot = ps[0] + ps[1] + ps[2];
    float inv = rsqrtf(tot / 192.f + 1e-5f);
    outp[idx] = f2b(r * inv * w[t]);
}

// ---------------- bf16 MFMA GEMM, BM=128/BN=64: C[M,N] = A[M,K] * W[N,K]^T ----------------
template<int OUTBF>
__global__ __launch_bounds__(256) void gemm_bf16(const ushort_t* __restrict__ A,
                                                 const ushort_t* __restrict__ W,
                                                 void* __restrict__ C,
                                                 int M, int N, int K, int ldc) {
    __shared__ ushort_t As[128 * 40];
    __shared__ ushort_t Bs[64 * 40];
    int tid = threadIdx.x;
    int m0 = blockIdx.y * 128, n0 = blockIdx.x * 64;
    int row = tid >> 2;
    int k8  = (tid & 3) * 8;
    int lane = tid & 63;
    int w = tid >> 6;
    int wr = w >> 1, wc = w & 1;
    int lr = lane & 15;
    int lk = (lane >> 4) * 8;
    f32x4 acc[4][2];
    #pragma unroll
    for (int i = 0; i < 4; i++)
        #pragma unroll
        for (int j = 0; j < 2; j++) acc[i][j] = (f32x4){0.f, 0.f, 0.f, 0.f};

    for (int k0 = 0; k0 < K; k0 += 32) {
        #pragma unroll
        for (int hhalf = 0; hhalf < 2; hhalf++) {
            int r = row + hhalf * 64;
            int m = m0 + r;
            bf16x8 v = {0,0,0,0,0,0,0,0};
            if (m < M) v = *(const bf16x8*)(A + (size_t)m * K + k0 + k8);
            *(bf16x8*)(&As[r * 40 + k8]) = v;
        }
        {
            int n = n0 + row;
            bf16x8 v = {0,0,0,0,0,0,0,0};
            if (n < N) v = *(const bf16x8*)(W + (size_t)n * K + k0 + k8);
            *(bf16x8*)(&Bs[row * 40 + k8]) = v;
        }
        __syncthreads();
        bf16x8 af[4], bfr[2];
        #pragma unroll
        for (int mi = 0; mi < 4; mi++)
            af[mi] = *(const bf16x8*)(&As[(wr * 64 + mi * 16 + lr) * 40 + lk]);
        #pragma unroll
        for (int ni = 0; ni < 2; ni++)
            bfr[ni] = *(const bf16x8*)(&Bs[(wc * 32 + ni * 16 + lr) * 40 + lk]);
        #pragma unroll
        for (int mi = 0; mi < 4; mi++)
            #pragma unroll
            for (int ni = 0; ni < 2; ni++)
                acc[mi][ni] = __builtin_amdgcn_mfma_f32_16x16x32_bf16(af[mi], bfr[ni], acc[mi][ni], 0, 0, 0);
        __syncthreads();
    }
    int rbase = (lane >> 4) * 4;
    #pragma unroll
    for (int mi = 0; mi < 4; mi++) {
        #pragma unroll
        for (int ni = 0; ni < 2; ni++) {
            #pragma unroll
            for (int r = 0; r < 4; r++) {
                int m = m0 + wr * 64 + mi * 16 + rbase + r;
                int n = n0 + wc * 32 + ni * 16 + lr;
                if (m < M && n < N) {
                    if (OUTBF) ((ushort_t*)C)[(size_t)m * ldc + n] = f2b(acc[mi][ni][r]);
                    else       ((float*)C)[(size_t)m * ldc + n] = acc[mi][ni][r];
                }
            }
        }
    }
}

// ---------------- bf16 MFMA GEMM, BM=64/BN=64, dual-dir (xproj) ----------------
__global__ __launch_bounds__(256) void gemm_xproj(const ushort_t* __restrict__ A0, const ushort_t* __restrict__ A1,
                                                  const ushort_t* __restrict__ W0, const ushort_t* __restrict__ W1,
                                                  float* __restrict__ C0, float* __restrict__ C1,
                                                  int M, int N, int K, int ldc) {
    __shared__ ushort_t As[64 * 40];
    __shared__ ushort_t Bs[64 * 40];
    int dir = blockIdx.z;
    const ushort_t* A = dir ? A1 : A0;
    const ushort_t* W = dir ? W1 : W0;
    float* C = dir ? C1 : C0;
    int tid = threadIdx.x;
    int m0 = blockIdx.y * 64, n0 = blockIdx.x * 64;
    int row = tid >> 2;
    int k8  = (tid & 3) * 8;
    int lane = tid & 63;
    int w = tid >> 6;
    int wr = w >> 1, wc = w & 1;
    int lr = lane & 15;
    int lk = (lane >> 4) * 8;
    f32x4 acc[2][2];
    #pragma unroll
    for (int i = 0; i < 2; i++)
        #pragma unroll
        for (int j = 0; j < 2; j++) acc[i][j] = (f32x4){0.f, 0.f, 0.f, 0.f};

    for (int k0 = 0; k0 < K; k0 += 32) {
        {
            int m = m0 + row;
            bf16x8 v = {0,0,0,0,0,0,0,0};
            if (m < M) v = *(const bf16x8*)(A + (size_t)m * K + k0 + k8);
            *(bf16x8*)(&As[row * 40 + k8]) = v;
            int n = n0 + row;
            bf16x8 wv = {0,0,0,0,0,0,0,0};
            if (n < N) wv = *(const bf16x8*)(W + (size_t)n * K + k0 + k8);
            *(bf16x8*)(&Bs[row * 40 + k8]) = wv;
        }
        __syncthreads();
        bf16x8 af[2], bfr[2];
        #pragma unroll
        for (int mi = 0; mi < 2; mi++)
            af[mi] = *(const bf16x8*)(&As[(wr * 32 + mi * 16 + lr) * 40 + lk]);
        #pragma unroll
        for (int ni = 0; ni < 2; ni++)
            bfr[ni] = *(const bf16x8*)(&Bs[(wc * 32 + ni * 16 + lr) * 40 + lk]);
        #pragma unroll
        for (int mi = 0; mi < 2; mi++)
            #pragma unroll
            for (int ni = 0; ni < 2; ni++)
                acc[mi][ni] = __builtin_amdgcn_mfma_f32_16x16x32_bf16(af[mi], bfr[ni], acc[mi][ni], 0, 0, 0);
        __syncthreads();
    }
    int rbase = (lane >> 4) * 4;
    #pragma unroll
    for (int mi = 0; mi < 2; mi++) {
        #pragma unroll
        for (int ni = 0; ni < 2; ni++) {
            #pragma unroll
            for (int r = 0; r < 4; r++) {
                int m = m0 + wr * 32 + mi * 16 + rbase + r;
                int n = n0 + wc * 32 + ni * 16 + lr;
                if (m < M && n < N) C[(size_t)m * ldc + n] = acc[mi][ni][r];
            }
        }
    }
}

// ---------------- out_proj GEMM BM=32/BN=192 + fused dir-combine + residual + RMSNorm ----------------
template<int FINAL>
__global__ __launch_bounds__(256) void gemm_outnorm(const ushort_t* __restrict__ yf, const ushort_t* __restrict__ yr,
                                                    const ushort_t* __restrict__ W, float* __restrict__ res,
                                                    const float* __restrict__ nw, void* __restrict__ outp) {
    __shared__ ushort_t As[32 * 40];
    __shared__ ushort_t Bs[192 * 40];
    __shared__ float psums[4 * 32];
    const int K = 384;
    int tid = threadIdx.x;
    int m0 = blockIdx.y * 32;
    int lane = tid & 63;
    int w = tid >> 6;
    int lr = lane & 15;
    int hi2 = lane >> 4;
    int lk = hi2 * 8;
    f32x4 acc[2][3];
    #pragma unroll
    for (int i = 0; i < 2; i++)
        #pragma unroll
        for (int j = 0; j < 3; j++) acc[i][j] = (f32x4){0.f, 0.f, 0.f, 0.f};

    int arow = tid >> 2;
    int k8 = (tid & 3) * 8;
    size_t rowfA = 0, rowrA = 0;
    if (tid < 128) {
        int m_ld = m0 + arow;
        int bb = m_ld / SEQL;
        int ll = m_ld - bb * SEQL;
        rowfA = (size_t)m_ld * 384;
        rowrA = ((size_t)bb * SEQL + (SEQL - 1 - ll)) * 384;
    }

    for (int k0 = 0; k0 < K; k0 += 32) {
        if (tid < 128) {
            bf16x8 vf = *(const bf16x8*)(yf + rowfA + k0 + k8);
            bf16x8 vr = *(const bf16x8*)(yr + rowrA + k0 + k8);
            bf16x8 v;
            #pragma unroll
            for (int j = 0; j < 8; j++) {
                float a = b2f((ushort_t)vf[j]);
                float b2 = b2f((ushort_t)vr[j]);
                v[j] = (short)f2b(0.5f * (a + b2));
            }
            *(bf16x8*)(&As[arow * 40 + k8]) = v;
        }
        #pragma unroll
        for (int s = 0; s < 3; s++) {
            int n = arow + s * 64;
            *(bf16x8*)(&Bs[n * 40 + k8]) = *(const bf16x8*)(W + (size_t)n * K + k0 + k8);
        }
        __syncthreads();
        bf16x8 af[2], bfr[3];
        #pragma unroll
        for (int mi = 0; mi < 2; mi++)
            af[mi] = *(const bf16x8*)(&As[(mi * 16 + lr) * 40 + lk]);
        #pragma unroll
        for (int ni = 0; ni < 3; ni++)
            bfr[ni] = *(const bf16x8*)(&Bs[(w * 48 + ni * 16 + lr) * 40 + lk]);
        #pragma unroll
        for (int mi = 0; mi < 2; mi++)
            #pragma unroll
            for (int ni = 0; ni < 3; ni++)
                acc[mi][ni] = __builtin_amdgcn_mfma_f32_16x16x32_bf16(af[mi], bfr[ni], acc[mi][ni], 0, 0, 0);
        __syncthreads();
    }

    #pragma unroll
    for (int mi = 0; mi < 2; mi++) {
        #pragma unroll
        for (int r = 0; r < 4; r++) {
            int m = m0 + mi * 16 + hi2 * 4 + r;
            #pragma unroll
            for (int ni = 0; ni < 3; ni++) {
                int col = w * 48 + ni * 16 + lr;
                acc[mi][ni][r] += res[(size_t)m * 192 + col];
            }
        }
    }
    float pp[2][4];
    #pragma unroll
    for (int mi = 0; mi < 2; mi++)
        #pragma unroll
        for (int r = 0; r < 4; r++) {
            float s = acc[mi][0][r] * acc[mi][0][r];
            s = fmaf(acc[mi][1][r], acc[mi][1][r], s);
            s = fmaf(acc[mi][2][r], acc[mi][2][r], s);
            pp[mi][r] = s;
        }
    #pragma unroll
    for (int mask = 1; mask < 16; mask <<= 1)
        #pragma unroll
        for (int mi = 0; mi < 2; mi++)
            #pragma unroll
            for (int r = 0; r < 4; r++)
                pp[mi][r] += __shfl_xor(pp[mi][r], mask);
    if (lr == 0) {
        #pragma unroll
        for (int mi = 0; mi < 2; mi++)
            #pragma unroll
            for (int r = 0; r < 4; r++)
                psums[w * 32 + mi * 16 + hi2 * 4 + r] = pp[mi][r];
    }
    __syncthreads();
    float inv[2][4];
    #pragma unroll
    for (int mi = 0; mi < 2; mi++)
        #pragma unroll
        for (int r = 0; r < 4; r++) {
            int idx = mi * 16 + hi2 * 4 + r;
            float tot = psums[idx] + psums[32 + idx] + psums[64 + idx] + psums[96 + idx];
            inv[mi][r] = rsqrtf(tot / 192.f + 1e-5f);
        }
    #pragma unroll
    for (int mi = 0; mi < 2; mi++) {
        #pragma unroll
        for (int ni = 0; ni < 3; ni++) {
            int col = w * 48 + ni * 16 + lr;
            float nwc = nw[col];
            #pragma unroll
            for (int r = 0; r < 4; r++) {
                int m = m0 + mi * 16 + hi2 * 4 + r;
                float v = acc[mi][ni][r];
                if (!FINAL) res[(size_t)m * 192 + col] = v;
                float o = v * inv[mi][r] * nwc;
                if (FINAL) ((float*)outp)[(size_t)m * 192 + col] = o;
                else       ((ushort_t*)outp)[(size_t)m * 192 + col] = f2b(o);
            }
        }
    }
}

// ---------------- causal depthwise conv (k=4) + SiLU, rolling window, both dirs ----------------
__global__ __launch_bounds__(384) void conv_silu_k(const ushort_t* __restrict__ xz,
                                                   const float* __restrict__ cw, const float* __restrict__ cb,
                                                   const float* __restrict__ cwb, const float* __restrict__ cbb,
                                                   ushort_t* __restrict__ xcf, ushort_t* __restrict__ xcr) {
    int d = threadIdx.x;
    int lc = blockIdx.x;
    int b = blockIdx.y;
    int dir = blockIdx.z;
    int lstart = lc * CCH;
    int lend = (lstart + CCH < SEQL) ? (lstart + CCH) : SEQL;
    const float* w = dir ? cwb : cw;
    const float* bias = dir ? cbb : cb;
    float4 wv = *(const float4*)(w + d * 4);
    float bs = bias[d];
    ushort_t* out = dir ? xcr : xcf;
    size_t base = (size_t)b * SEQL;
    float win0 = 0.f, win1 = 0.f, win2 = 0.f;
    if (lstart - 3 >= 0) win0 = b2f(xz[(base + (dir ? (SEQL-1-(lstart-3)) : (lstart-3))) * 768 + d]);
    if (lstart - 2 >= 0) win1 = b2f(xz[(base + (dir ? (SEQL-1-(lstart-2)) : (lstart-2))) * 768 + d]);
    if (lstart - 1 >= 0) win2 = b2f(xz[(base + (dir ? (SEQL-1-(lstart-1)) : (lstart-1))) * 768 + d]);
    float xcur = b2f(xz[(base + (dir ? (SEQL-1-lstart) : lstart)) * 768 + d]);
    for (int l = lstart; l < lend; l++) {
        int ln = l + 1;
        float xnext = 0.f;
        if (ln < lend) xnext = b2f(xz[(base + (dir ? (SEQL-1-ln) : ln)) * 768 + d]);
        float a = bs;
        a = fmaf(wv.x, win0, a);
        a = fmaf(wv.y, win1, a);
        a = fmaf(wv.z, win2, a);
        a = fmaf(wv.w, xcur, a);
        float s = a / (1.f + __expf(-a));
        out[(base + l) * 384 + d] = f2b(s);
        win0 = win1; win1 = win2; win2 = xcur; xcur = xnext;
    }
}

// ============ chunked selective scan: 2 channels/thread, rows direct-from-global ============
__global__ __launch_bounds__(192) void scan_p1(const ushort_t* __restrict__ xcf, const ushort_t* __restrict__ xcr,
                                               const float* __restrict__ dtbcf, const float* __restrict__ dtbcr,
                                               const float* __restrict__ dwf, const float* __restrict__ dwr,
                                               const float* __restrict__ dbf, const float* __restrict__ dbr,
                                               const float* __restrict__ Alf, const float* __restrict__ Alb,
                                               float* __restrict__ Sbuf, float* __restrict__ sumdt,
                                               const int* __restrict__ flagp) {
    int t = threadIdx.x;
    int d0 = t, d1 = t + 192;
    int c = blockIdx.x;
    int b = blockIdx.y, dir = blockIdx.z;
    int bd = b * 2 + dir;
    const ushort_t* xcp = dir ? xcr : xcf;
    const float* pbc = (dir ? dtbcr : dtbcf) + (size_t)b * SEQL * 44;
    int lstart = c * CL;
    int clen = (lstart + CL < SEQL) ? CL : (SEQL - lstart);
    size_t rowbase = (size_t)b * SEQL + lstart;

    float dw0[12], dw1[12];
    {
        const float* dwp = (dir ? dwr : dwf);
        #pragma unroll
        for (int r = 0; r < 12; r++) dw0[r] = dwp[d0 * 12 + r];
        #pragma unroll
        for (int r = 0; r < 12; r++) dw1[r] = dwp[d1 * 12 + r];
    }
    float db0 = (dir ? dbr : dbf)[d0];
    float db1 = (dir ? dbr : dbf)[d1];
    bool fast = (*flagp != 0);
    float S0[16], S1[16];
    #pragma unroll
    for (int n = 0; n < 16; n++) { S0[n] = 0.f; S1[n] = 0.f; }
    float ss0 = 0.f, ss1 = 0.f;

    if (fast) {
        float x0 = b2f(xcp[rowbase * 384 + d0]);
        float x1 = b2f(xcp[rowbase * 384 + d1]);
        for (int l = 0; l < clen; l++) {
            int ln = (l + 1 < clen) ? (l + 1) : l;
            float x0n = b2f(xcp[(rowbase + ln) * 384 + d0]);
            float x1n = b2f(xcp[(rowbase + ln) * 384 + d1]);
            const float* rp = pbc + (size_t)(lstart + l) * 44;   // wave-uniform
            float4 t0 = *(const float4*)(rp);
            float4 t1 = *(const float4*)(rp + 4);
            float4 t2 = *(const float4*)(rp + 8);
            float4 B0 = *(const float4*)(rp + 12);
            float4 B1 = *(const float4*)(rp + 16);
            float4 B2 = *(const float4*)(rp + 20);
            float4 B3 = *(const float4*)(rp + 24);
            float tv[12] = {t0.x,t0.y,t0.z,t0.w, t1.x,t1.y,t1.z,t1.w, t2.x,t2.y,t2.z,t2.w};
            float a0 = db0, a1 = db1;
            #pragma unroll
            for (int r = 0; r < 12; r++) {
                a0 = fmaf(tv[r], dw0[r], a0);
                a1 = fmaf(tv[r], dw1[r], a1);
            }
            float dt0 = softplus_fast(a0);
            float dt1 = softplus_fast(a1);
            ss0 += dt0; ss1 += dt1;
            float dtx0 = dt0 * x0, dtx1 = dt1 * x1;
            float dA0[16], dA1[16];
            pow_ladder(__expf(-dt0), dA0);
            pow_ladder(__expf(-dt1), dA1);
            float Bv[16] = {B0.x,B0.y,B0.z,B0.w, B1.x,B1.y,B1.z,B1.w,
                            B2.x,B2.y,B2.z,B2.w, B3.x,B3.y,B3.z,B3.w};
            #pragma unroll
            for (int n = 0; n < 16; n++) {
                S0[n] = fmaf(S0[n], dA0[n], dtx0 * Bv[n]);
                S1[n] = fmaf(S1[n], dA1[n], dtx1 * Bv[n]);
            }
            x0 = x0n; x1 = x1n;
        }
    } else {
        const float* alog = (dir ? Alb : Alf);
        float A0[16], A1[16];
        #pragma unroll
        for (int n = 0; n < 16; n++) A0[n] = -__expf(alog[d0 * 16 + n]);
        #pragma unroll
        for (int n = 0; n < 16; n++) A1[n] = -__expf(alog[d1 * 16 + n]);
        for (int l = 0; l < clen; l++) {
            const float* rp = pbc + (size_t)(lstart + l) * 44;
            float a0 = db0, a1 = db1;
            #pragma unroll
            for (int r = 0; r < 12; r++) {
                a0 = fmaf(rp[r], dw0[r], a0);
                a1 = fmaf(rp[r], dw1[r], a1);
            }
            float dt0 = softplus_f(a0);
            float dt1 = softplus_f(a1);
            ss0 += dt0; ss1 += dt1;
            float x0 = b2f(xcp[(rowbase + l) * 384 + d0]);
            float x1 = b2f(xcp[(rowbase + l) * 384 + d1]);
            float dtx0 = dt0 * x0, dtx1 = dt1 * x1;
            #pragma unroll
            for (int n = 0; n < 16; n++) {
                S0[n] = fmaf(S0[n], __expf(dt0 * A0[n]), dtx0 * rp[12 + n]);
                S1[n] = fmaf(S1[n], __expf(dt1 * A1[n]), dtx1 * rp[12 + n]);
            }
        }
    }
    float* spb = Sbuf + ((size_t)bd * NC + c) * 6144;
    #pragma unroll
    for (int j = 0; j < 4; j++) {
        *(float4*)(spb + d0 * 16 + j * 4) = make_float4(S0[j*4], S0[j*4+1], S0[j*4+2], S0[j*4+3]);
        *(float4*)(spb + d1 * 16 + j * 4) = make_float4(S1[j*4], S1[j*4+1], S1[j*4+2], S1[j*4+3]);
    }
    sumdt[((size_t)bd * NC + c) * 384 + d0] = ss0;
    sumdt[((size_t)bd * NC + c) * 384 + d1] = ss1;
}

// pass 2: O(NC) prefix; converts Sbuf in place into h_in per chunk. 1 thread per (bd,d,n).
__global__ __launch_bounds__(256) void scan_mid(float* __restrict__ Sbuf, const float* __restrict__ sumdt,
                                                const float* __restrict__ Alf, const float* __restrict__ Alb,
                                                const int* __restrict__ flagp) {
    int gid = blockIdx.x * 256 + threadIdx.x;
    int n = gid & 15;
    int rest = gid >> 4;
    int d = rest % 384;
    int bd = rest / 384;
    int dir = bd & 1;
    bool fast = (*flagp != 0);
    float A = fast ? -(float)(n + 1) : -__expf((dir ? Alb : Alf)[d * 16 + n]);
    float h = 0.f;
    #pragma unroll
    for (int c = 0; c < NC; c++) {
        size_t si = ((size_t)bd * NC + c) * 6144 + d * 16 + n;
        float S = Sbuf[si];
        float sd = sumdt[((size_t)bd * NC + c) * 384 + d];
        Sbuf[si] = h;
        h = fmaf(h, __expf(A * sd), S);
    }
}

// pass 3: read own h_in, re-scan chunk, emit y*silu(z) bf16. 2 channels/thread.
__global__ __launch_bounds__(192) void scan_p3(const ushort_t* __restrict__ xcf, const ushort_t* __restrict__ xcr,
                                               const float* __restrict__ dtbcf, const float* __restrict__ dtbcr,
                                               const float* __restrict__ dwf, const float* __restrict__ dwr,
                                               const float* __restrict__ dbf, const float* __restrict__ dbr,
                                               const float* __restrict__ Alf, const float* __restrict__ Alb,
                                               const float* __restrict__ Df, const float* __restrict__ Db,
                                               const ushort_t* __restrict__ xz,
                                               const float* __restrict__ Sbuf,
                                               ushort_t* __restrict__ ybf, ushort_t* __restrict__ ybr,
                                               const int* __restrict__ flagp) {
    int t = threadIdx.x;
    int d0 = t, d1 = t + 192;
    int c = blockIdx.x;
    int b = blockIdx.y, dir = blockIdx.z;
    int bd = b * 2 + dir;
    const ushort_t* xcp = dir ? xcr : xcf;
    const float* pbc = (dir ? dtbcr : dtbcf) + (size_t)b * SEQL * 44;
    ushort_t* yb = dir ? ybr : ybf;
    int lstart = c * CL;
    int clen = (lstart + CL < SEQL) ? CL : (SEQL - lstart);
    size_t rowbase = (size_t)b * SEQL + lstart;
    size_t seqbase = (size_t)b * SEQL;

    float dw0[12], dw1[12];
    {
        const float* dwp = (dir ? dwr : dwf);
        #pragma unroll
        for (int r = 0; r < 12; r++) dw0[r] = dwp[d0 * 12 + r];
        #pragma unroll
        for (int r = 0; r < 12; r++) dw1[r] = dwp[d1 * 12 + r];
    }
    float db0 = (dir ? dbr : dbf)[d0];
    float db1 = (dir ? dbr : dbf)[d1];
    float Dp0 = (dir ? Db : Df)[d0];
    float Dp1 = (dir ? Db : Df)[d1];
    bool fast = (*flagp != 0);
    float h0[16], h1[16];
    {
        const float* spb = Sbuf + ((size_t)bd * NC + c) * 6144;
        #pragma unroll
        for (int j = 0; j < 4; j++) {
            float4 hv0 = *(const float4*)(spb + d0 * 16 + j * 4);
            float4 hv1 = *(const float4*)(spb + d1 * 16 + j * 4);
            h0[j*4] = hv0.x; h0[j*4+1] = hv0.y; h0[j*4+2] = hv0.z; h0[j*4+3] = hv0.w;
            h1[j*4] = hv1.x; h1[j*4+1] = hv1.y; h1[j*4+2] = hv1.z; h1[j*4+3] = hv1.w;
        }
    }

    if (fast) {
        float x0 = b2f(xcp[rowbase * 384 + d0]);
        float x1 = b2f(xcp[rowbase * 384 + d1]);
        size_t zr0 = (dir ? (seqbase + SEQL - 1 - lstart) : rowbase) * 768 + 384;
        float z0 = b2f(xz[zr0 + d0]);
        float z1 = b2f(xz[zr0 + d1]);
        for (int l = 0; l < clen; l++) {
            int ln = (l + 1 < clen) ? (l + 1) : l;
            float x0n = b2f(xcp[(rowbase + ln) * 384 + d0]);
            float x1n = b2f(xcp[(rowbase + ln) * 384 + d1]);
            size_t zrn = (dir ? (seqbase + SEQL - 1 - (lstart + ln)) : (rowbase + ln)) * 768 + 384;
            float z0n = b2f(xz[zrn + d0]);
            float z1n = b2f(xz[zrn + d1]);
            const float* rp = pbc + (size_t)(lstart + l) * 44;   // wave-uniform
            float4 t0 = *(const float4*)(rp);
            float4 t1 = *(const float4*)(rp + 4);
            float4 t2 = *(const float4*)(rp + 8);
            float4 B0 = *(const float4*)(rp + 12);
            float4 B1 = *(const float4*)(rp + 16);
            float4 B2 = *(const float4*)(rp + 20);
            float4 B3 = *(const float4*)(rp + 24);
            float4 C0 = *(const float4*)(rp + 28);
            float4 C1 = *(const float4*)(rp + 32);
            float4 C2 = *(const float4*)(rp + 36);
            float4 C3 = *(const float4*)(rp + 40);
            float tv[12] = {t0.x,t0.y,t0.z,t0.w, t1.x,t1.y,t1.z,t1.w, t2.x,t2.y,t2.z,t2.w};
            float a0 = db0, a1 = db1;
            #pragma unroll
            for (int r = 0; r < 12; r++) {
                a0 = fmaf(tv[r], dw0[r], a0);
                a1 = fmaf(tv[r], dw1[r], a1);
            }
            float dt0 = softplus_fast(a0);
            float dt1 = softplus_fast(a1);
            float dtx0 = dt0 * x0, dtx1 = dt1 * x1;
            float dA0[16], dA1[16];
            pow_ladder(__expf(-dt0), dA0);
            pow_ladder(__expf(-dt1), dA1);
            float Bv[16] = {B0.x,B0.y,B0.z,B0.w, B1.x,B1.y,B1.z,B1.w,
                            B2.x,B2.y,B2.z,B2.w, B3.x,B3.y,B3.z,B3.w};
            float Cv[16] = {C0.x,C0.y,C0.z,C0.w, C1.x,C1.y,C1.z,C1.w,
                            C2.x,C2.y,C2.z,C2.w, C3.x,C3.y,C3.z,C3.w};
            float y0 = 0.f, y1 = 0.f;
            #pragma unroll
            for (int n = 0; n < 16; n++) {
                h0[n] = fmaf(h0[n], dA0[n], dtx0 * Bv[n]);
                h1[n] = fmaf(h1[n], dA1[n], dtx1 * Bv[n]);
                y0 = fmaf(h0[n], Cv[n], y0);
                y1 = fmaf(h1[n], Cv[n], y1);
            }
            y0 = fmaf(Dp0, x0, y0);
            y1 = fmaf(Dp1, x1, y1);
            float sz0 = z0 / (1.f + __expf(-z0));
            float sz1 = z1 / (1.f + __expf(-z1));
            yb[(rowbase + l) * 384 + d0] = f2b(y0 * sz0);
            yb[(rowbase + l) * 384 + d1] = f2b(y1 * sz1);
            x0 = x0n; x1 = x1n; z0 = z0n; z1 = z1n;
        }
    } else {
        const float* alog = (dir ? Alb : Alf);
        float A0[16], A1[16];
        #pragma unroll
        for (int n = 0; n < 16; n++) A0[n] = -__expf(alog[d0 * 16 + n]);
        #pragma unroll
        for (int n = 0; n < 16; n++) A1[n] = -__expf(alog[d1 * 16 + n]);
        for (int l = 0; l < clen; l++) {
            const float* rp = pbc + (size_t)(lstart + l) * 44;
            float a0 = db0, a1 = db1;
            #pragma unroll
            for (int r = 0; r < 12; r++) {
                a0 = fmaf(rp[r], dw0[r], a0);
                a1 = fmaf(rp[r], dw1[r], a1);
            }
            float dt0 = softplus_f(a0);
            float dt1 = softplus_f(a1);
            float x0 = b2f(xcp[(rowbase + l) * 384 + d0]);
            float x1 = b2f(xcp[(rowbase + l) * 384 + d1]);
            size_t zr = (dir ? (seqbase + SEQL - 1 - (lstart + l)) : (rowbase + l)) * 768 + 384;
            float z0 = b2f(xz[zr + d0]);
            float z1 = b2f(xz[zr + d1]);
            float dtx0 = dt0 * x0, dtx1 = dt1 * x1;
            float y0 = 0.f, y1 = 0.f;
            #pragma unroll
            for (int n = 0; n < 16; n++) {
                h0[n] = fmaf(h0[n], __expf(dt0 * A0[n]), dtx0 * rp[12 + n]);
                h1[n] = fmaf(h1[n], __expf(dt1 * A1[n]), dtx1 * rp[12 + n]);
                y0 = fmaf(h0[n], rp[28 + n], y0);
                y1 = fmaf(h1[n], rp[28 + n], y1);
            }
            y0 = fmaf(Dp0, x0, y0);
            y1 = fmaf(Dp1, x1, y1);
            float sz0 = z0 / (1.f + __expf(-z0));
            float sz1 = z1 / (1.f + __expf(-z1));
            yb[(rowbase + l) * 384 + d0] = f2b(y0 * sz0);
            yb[(rowbase + l) * 384 + d1] = f2b(y1 * sz1);
        }
    }
}

extern "C" void kernel_launch(void* const* d_in, const int* in_sizes, int n_in,
                              void* d_out, int out_size, void* d_ws, size_t ws_size,
                              hipStream_t stream) {
    const float* x         = (const float*)d_in[0];
    const float* patch_w   = (const float*)d_in[1];
    const float* patch_b   = (const float*)d_in[2];
    const float* cls_token = (const float*)d_in[3];
    const float* pos_embed = (const float*)d_in[4];
    const float* norm_w    = (const float*)d_in[5];
    const float* in_proj_w = (const float*)d_in[6];
    const float* conv_w    = (const float*)d_in[7];
    const float* conv_b    = (const float*)d_in[8];
    const float* xproj_w   = (const float*)d_in[9];
    const float* dtproj_w  = (const float*)d_in[10];
    const float* dt_bias   = (const float*)d_in[11];
    const float* A_log     = (const float*)d_in[12];
    const float* Dskip     = (const float*)d_in[13];
    const float* conv_w_b  = (const float*)d_in[14];
    const float* conv_b_b  = (const float*)d_in[15];
    const float* xproj_w_b = (const float*)d_in[16];
    const float* dtproj_w_b= (const float*)d_in[17];
    const float* dt_bias_b = (const float*)d_in[18];
    const float* A_log_b   = (const float*)d_in[19];
    const float* Dskip_b   = (const float*)d_in[20];
    const float* out_proj_w= (const float*)d_in[21];
    const float* norm_f_w  = (const float*)d_in[22];

    float* ws = (float*)d_ws;
    size_t off = 0;
    float* res   = ws + off; off += (size_t)NTOK * 192;
    float* hbuf  = ws + off; off += (size_t)NTOK * 192;
    ushort_t* xzb = (ushort_t*)(ws + off); off += (size_t)NTOK * 384;   // NTOK*768 ushorts; also Apatch
    ushort_t* hnb = (ushort_t*)(ws + off); off += (size_t)NTOK * 96;
    ushort_t* xcfb = (ushort_t*)(ws + off); off += (size_t)NTOK * 192;
    ushort_t* xcrb = (ushort_t*)(ws + off); off += (size_t)NTOK * 192;
    float* dtbcf = ws + off; off += (size_t)NTOK * 44;
    float* dtbcr = ws + off; off += (size_t)NTOK * 44;
    ushort_t* ybf = (ushort_t*)(ws + off); off += (size_t)NTOK * 192;
    ushort_t* ybr = (ushort_t*)(ws + off); off += (size_t)NTOK * 192;
    float* Sbuf  = ws + off; off += (size_t)BATCH * 2 * NC * 6144;      // also Ppatch fp32
    float* sumdt = ws + off; off += (size_t)BATCH * 2 * NC * 384;
    int* flagp   = (int*)(ws + off); off += 4;
    ushort_t* wb = (ushort_t*)(ws + off);
    ushort_t* winb   = wb;
    ushort_t* woutb  = winb  + 3538944;
    ushort_t* xpfb   = woutb + 1769472;
    ushort_t* xprb   = xpfb  + 405504;
    ushort_t* patchwb= xprb  + 405504;

    ushort_t* Apatch = xzb;
    float* Ppatch = Sbuf;

    convert_k<<<(3538944/4 + 255)/256, 256, 0, stream>>>(in_proj_w, winb, 3538944);
    convert_k<<<(1769472/4 + 255)/256, 256, 0, stream>>>(out_proj_w, woutb, 1769472);
    convert_k<<<(405504/4 + 255)/256, 256, 0, stream>>>(xproj_w, xpfb, 405504);
    convert_k<<<(405504/4 + 255)/256, 256, 0, stream>>>(xproj_w_b, xprb, 405504);
    convert_k<<<(147456/4 + 255)/256, 256, 0, stream>>>(patch_w, patchwb, 147456);

    hipMemsetAsync(res, 0, (size_t)NTOK * 192 * sizeof(float), stream);
    hipMemsetAsync(flagp, 1, 4, stream);   // nonzero = fast path allowed
    checkA_k<<<(DEPTH*384*16 + 255)/256, 256, 0, stream>>>(A_log, A_log_b, flagp);

    rearrange_k<<<6144, 256, 0, stream>>>(x, Apatch);
    gemm_bf16<0><<<dim3(3, 64), 256, 0, stream>>>(Apatch, patchwb, Ppatch, 8192, 192, 768, 192);
    assemble_k<<<dim3(SEQL, BATCH), 192, 0, stream>>>(Ppatch, patch_b, cls_token, pos_embed, hbuf);
    addnorm_k<<<NTOK, 192, 0, stream>>>(res, hbuf, norm_w, hnb);   // layer-0 norm

    for (int i = 0; i < DEPTH; i++) {
        const float* cwf  = conv_w + (size_t)i * 384 * 4;
        const float* cbf  = conv_b + (size_t)i * 384;
        const float* cwr  = conv_w_b + (size_t)i * 384 * 4;
        const float* cbr  = conv_b_b + (size_t)i * 384;
        const float* dpf  = dtproj_w + (size_t)i * 384 * 12;
        const float* dpr  = dtproj_w_b + (size_t)i * 384 * 12;
        const float* dbf  = dt_bias + (size_t)i * 384;
        const float* dbr  = dt_bias_b + (size_t)i * 384;
        const float* alf  = A_log + (size_t)i * 384 * 16;
        const float* alr  = A_log_b + (size_t)i * 384 * 16;
        const float* dsf  = Dskip + (size_t)i * 384;
        const float* dsr  = Dskip_b + (size_t)i * 384;

        gemm_bf16<1><<<dim3(12, 65), 256, 0, stream>>>(hnb, winb + (size_t)i * 768 * 192, xzb,
                                                       NTOK, 768, 192, 768);
        conv_silu_k<<<dim3((SEQL + CCH - 1) / CCH, BATCH, 2), 384, 0, stream>>>(xzb, cwf, cbf, cwr, cbr, xcfb, xcrb);
        gemm_xproj<<<dim3(1, 129, 2), 256, 0, stream>>>(xcfb, xcrb,
                                                        xpfb + (size_t)i * 44 * 384, xprb + (size_t)i * 44 * 384,
                                                        dtbcf, dtbcr, NTOK, 44, 384, 44);
        scan_p1<<<dim3(NC, BATCH, 2), 192, 0, stream>>>(xcfb, xcrb, dtbcf, dtbcr,
                                                        dpf, dpr, dbf, dbr, alf, alr, Sbuf, sumdt, flagp);
        scan_mid<<<(BATCH * 2 * 384 * 16) / 256, 256, 0, stream>>>(Sbuf, sumdt, alf, alr, flagp);
        scan_p3<<<dim3(NC, BATCH, 2), 192, 0, stream>>>(xcfb, xcrb, dtbcf, dtbcr,
                                                        dpf, dpr, dbf, dbr, alf, alr, dsf, dsr,
                                                        xzb, Sbuf, ybf, ybr, flagp);
        if (i < DEPTH - 1) {
            gemm_outnorm<0><<<dim3(1, NTOK / 32), 256, 0, stream>>>(ybf, ybr, woutb + (size_t)i * 192 * 384,
                                                                    res, norm_w + (size_t)(i + 1) * 192, hnb);
        } else {
            gemm_outnorm<1><<<dim3(1, NTOK / 32), 256, 0, stream>>>(ybf, ybr, woutb + (size_t)i * 192 * 384,
                                                                    res, norm_f_w, (float*)d_out);
        }
    }
}